// Round 9
// baseline (231.397 us; speedup 1.0000x reference)
//
#include <hip/hip_runtime.h>
#include <hip/hip_bf16.h>
#include <math.h>

typedef __attribute__((ext_vector_type(8))) short bf16x8;
typedef __attribute__((ext_vector_type(4))) short s16x4;
typedef __attribute__((ext_vector_type(4))) float f32x4;

constexpr int cB = 2, cS = 2048, cH = 16, cD = 64, cIn = 1024, cM = 1024;
constexpr float cLog2e = 1.4426950408889634f;

union BfPack { bf16x8 v; short s[8]; };

__device__ __forceinline__ short f2bf(float f) {
    union { float f; unsigned u; } v; v.f = f;
    unsigned r = v.u + 0x7fffu + ((v.u >> 16) & 1u);   // round-to-nearest-even
    return (short)(r >> 16);
}

__device__ __forceinline__ f32x4 mfma16(bf16x8 a, bf16x8 b, f32x4 c) {
    return __builtin_amdgcn_mfma_f32_16x16x32_bf16(a, b, c, 0, 0, 0);
}

__device__ __forceinline__ void async16(const short* g, short* l) {
    __builtin_amdgcn_global_load_lds(
        (const __attribute__((address_space(1))) unsigned*)(uintptr_t)g,
        (__attribute__((address_space(3))) unsigned*)(uintptr_t)l, 16, 0, 0);
}

// unaligned (4B-aligned) 16B vector load; gfx950 supports unaligned global
__device__ __forceinline__ f32x4 ld_f32x4_a4(const float* p) {
    f32x4 r;
    __builtin_memcpy(&r, p, 16);
    return r;
}

// kappa permutation of a key index within its 64-group (bit shuffle)
__device__ __forceinline__ int kappa64(int off) {
    return ((off >> 4) & 1) * 32 + ((off >> 2) & 3) * 8 +
           ((off >> 5) & 1) * 4 + (off & 3);
}

// ---------------------------------------------------------------------------
// Kernel 1: bias table bt[h][2048+delta] pre-scaled by log2e; mask tables:
// maskmul[b*S+s] (float 0/1, multiplies V) and mkp[b*S+kappa(s)] (bf16 0/1,
// A-operand of the denominator MFMA, kappa-permuted like V^T).
// ---------------------------------------------------------------------------
__global__ void bias_table_kernel(const float* __restrict__ rel_bias,
                                  const int* __restrict__ mask,
                                  float* __restrict__ bt,
                                  float* __restrict__ maskmul,
                                  short* __restrict__ mkp) {
    int idx = blockIdx.x * blockDim.x + threadIdx.x;
    if (idx < 4096) {
        float mv = (float)mask[idx];
        maskmul[idx] = mv;
        mkp[(idx & ~63) | kappa64(idx & 63)] = f2bf(mv);
    }
    if (idx >= 4095) return;
    int delta = idx - 2047;
    int rb = (delta > 0) ? 16 : 0;
    int ar = delta < 0 ? -delta : delta;
    int bucket;
    if (ar < 8) {
        bucket = rb + ar;
    } else {
        float rl = 8.0f + logf((float)ar * 0.125f) * 2.8853900817779268f;
        rl = fminf(rl, 15.0f);
        bucket = rb + (int)rl;
    }
    #pragma unroll
    for (int h = 0; h < cH; h++)
        bt[h * 4096 + 2048 + delta] = rel_bias[bucket * cH + h] * cLog2e;
}

// ---------------------------------------------------------------------------
// Kernel 2a: hidden fp32 -> bf16, flat.
// ---------------------------------------------------------------------------
__global__ __launch_bounds__(256) void conv_hidden_kernel(
    const float* __restrict__ h, short* __restrict__ hbf) {
    int t = blockIdx.x * 256 + threadIdx.x;
    const float4* src = (const float4*)h;
    float4 a = src[2 * t], b = src[2 * t + 1];
    BfPack p;
    p.s[0] = f2bf(a.x); p.s[1] = f2bf(a.y); p.s[2] = f2bf(a.z); p.s[3] = f2bf(a.w);
    p.s[4] = f2bf(b.x); p.s[5] = f2bf(b.y); p.s[6] = f2bf(b.z); p.s[7] = f2bf(b.w);
    ((bf16x8*)hbf)[t] = p.v;
}

// ---------------------------------------------------------------------------
// Kernel 2b: weights fp32 [K][N] -> bf16 TRANSPOSED Wt[z][N][K].
// Wq carries 0.125 * log2(e).
// ---------------------------------------------------------------------------
__global__ __launch_bounds__(256) void conv_wt_kernel(
    const float* __restrict__ Wq, const float* __restrict__ Wk,
    const float* __restrict__ Wv, const float* __restrict__ Wo,
    short* __restrict__ Wt) {
    const int z = blockIdx.z;
    const float* W = (z == 0) ? Wq : (z == 1) ? Wk : (z == 2) ? Wv : Wo;
    const float scale = (z == 0) ? 0.125f * cLog2e : 1.0f;
    const int n0 = blockIdx.x * 64, k0 = blockIdx.y * 64;
    __shared__ short sW[64][72];     // [k][n]
    const int t = threadIdx.x;
    const int r = t >> 2, c4 = (t & 3) * 16;
    {
        const float* src = W + (size_t)(k0 + r) * cM + n0 + c4;
        BfPack p[2];
        #pragma unroll
        for (int q = 0; q < 2; q++) {
            float4 x = ((const float4*)src)[2 * q];
            float4 y = ((const float4*)src)[2 * q + 1];
            p[q].s[0] = f2bf(x.x * scale); p[q].s[1] = f2bf(x.y * scale);
            p[q].s[2] = f2bf(x.z * scale); p[q].s[3] = f2bf(x.w * scale);
            p[q].s[4] = f2bf(y.x * scale); p[q].s[5] = f2bf(y.y * scale);
            p[q].s[6] = f2bf(y.z * scale); p[q].s[7] = f2bf(y.w * scale);
        }
        *(bf16x8*)&sW[r][c4] = p[0].v;
        *(bf16x8*)&sW[r][c4 + 8] = p[1].v;
    }
    __syncthreads();
    const int n = t >> 2, kc = (t & 3) * 16;
    BfPack o0, o1;
    #pragma unroll
    for (int j = 0; j < 8; j++) o0.s[j] = sW[kc + j][n];
    #pragma unroll
    for (int j = 0; j < 8; j++) o1.s[j] = sW[kc + 8 + j][n];
    short* dst = Wt + (size_t)z * cM * cIn + (size_t)(n0 + n) * cIn + k0 + kc;
    *(bf16x8*)dst = o0.v;
    *(bf16x8*)(dst + 8) = o1.v;
}

// ---------------------------------------------------------------------------
// GEMM core (m97-style): A[128][32], B[128][32] via global_load_lds.
// ---------------------------------------------------------------------------
template <bool SWAP>
__device__ __forceinline__ void gemm_core(
    const short* __restrict__ A, const short* __restrict__ Bt,
    short* smem, int m0, int c0, int tid, f32x4 (&acc)[4][4]) {
    short* sA = smem;
    short* sB = smem + 4096;
    const int w = tid >> 6, l = tid & 63;
    const int m16 = l & 15, g = l >> 4;
    const int srow = l >> 2, scol = (l & 3) * 8;
    const int mq = (w & 1) * 64, nq = (w >> 1) * 64;

    for (int k0 = 0; k0 < cIn; k0 += 32) {
        __syncthreads();
        async16(A + (size_t)(m0 + w * 16 + srow) * cIn + k0 + scol,
                sA + w * 512 + l * 8);
        async16(A + (size_t)(m0 + 64 + w * 16 + srow) * cIn + k0 + scol,
                sA + 2048 + w * 512 + l * 8);
        async16(Bt + (size_t)(c0 + w * 16 + srow) * cIn + k0 + scol,
                sB + w * 512 + l * 8);
        async16(Bt + (size_t)(c0 + 64 + w * 16 + srow) * cIn + k0 + scol,
                sB + 2048 + w * 512 + l * 8);
        __syncthreads();
        bf16x8 af[4], bf[4];
        #pragma unroll
        for (int i = 0; i < 4; i++)
            af[i] = *(const bf16x8*)(sA + (mq + i * 16 + m16) * 32 + g * 8);
        #pragma unroll
        for (int j = 0; j < 4; j++)
            bf[j] = *(const bf16x8*)(sB + (nq + j * 16 + m16) * 32 + g * 8);
        #pragma unroll
        for (int i = 0; i < 4; i++)
            #pragma unroll
            for (int j = 0; j < 4; j++)
                acc[i][j] = SWAP ? mfma16(bf[j], af[i], acc[i][j])
                                 : mfma16(af[i], bf[j], acc[i][j]);
    }
}

// ---------------------------------------------------------------------------
// Kernel 3: QKV GEMM. z=0 Q row-major (log2e-scaled), z=1 K row-major,
// z=2 V^T [b][h][d][kappa(s)] KAPPA-PERMUTED + PRE-MASKED, direct store.
// ---------------------------------------------------------------------------
__global__ __launch_bounds__(256) void gemm_qkv_kernel(
    const short* __restrict__ hbf, const short* __restrict__ Wt,
    const float* __restrict__ maskmul,
    short* __restrict__ Qrm, short* __restrict__ Krm, short* __restrict__ VT) {
    const int z = blockIdx.z;
    const short* Bt = Wt + (size_t)z * cM * cIn;
    const int m0 = blockIdx.y * 128, c0 = blockIdx.x * 128;
    __shared__ short smem[8192];
    const int tid = threadIdx.x, w = tid >> 6, l = tid & 63;
    const int m16 = l & 15, g = l >> 4;
    const int mq = (w & 1) * 64, nq = (w >> 1) * 64;
    f32x4 acc[4][4] = {};

    if (z <= 1) {
        gemm_core<false>(hbf, Bt, smem, m0, c0, tid, acc);
        short* dst = (z == 0) ? Qrm : Krm;
        #pragma unroll
        for (int i = 0; i < 4; i++)
            #pragma unroll
            for (int j = 0; j < 4; j++)
                #pragma unroll
                for (int r = 0; r < 4; r++)
                    dst[(size_t)(m0 + mq + i * 16 + g * 4 + r) * cM +
                        c0 + nq + j * 16 + m16] = f2bf(acc[i][j][r]);
    } else {
        gemm_core<true>(hbf, Bt, smem, m0, c0, tid, acc);
        #pragma unroll
        for (int i = 0; i < 4; i++) {
            const int srow_g = m0 + mq + i * 16 + m16;   // b*S + s
            const int bb = srow_g >> 11, ss = srow_g & 2047;
            const float sc = maskmul[bb * cS + ss];      // pre-mask V
            const int ssp = (ss & ~63) | kappa64(ss & 63);
            #pragma unroll
            for (int j = 0; j < 4; j++)
                #pragma unroll
                for (int r = 0; r < 4; r++) {
                    const int wcol = c0 + nq + j * 16 + g * 4 + r;  // h*64+d
                    VT[(((size_t)bb * cH + (wcol >> 6)) * cD + (wcol & 63)) * cS
                       + ssp] = f2bf(acc[i][j][r] * sc);
                }
        }
    }
}

// ---------------------------------------------------------------------------
// attention tile compute: 64 keys, buffers already staged.
// ---------------------------------------------------------------------------
__device__ __forceinline__ void attn_tile(
    const short* Kt, const short* Vt, const f32x4 (&bias)[4],
    const short* mkp_kt, bf16x8 qf0, bf16x8 qf1, int m16, int g,
    f32x4 (&o)[4], f32x4& lacc) {
    // denominator A-operand (mask, kappa order) — issue early
    bf16x8 amk0 = *(const bf16x8*)(mkp_kt + g * 8);
    bf16x8 amk1 = *(const bf16x8*)(mkp_kt + 32 + g * 8);
    BfPack pp[2];
    #pragma unroll
    for (int st = 0; st < 4; st++) {
        const short* kr = Kt + (st * 16 + m16) * 72 + g * 8;
        bf16x8 klo = *(const bf16x8*)kr;
        bf16x8 khi = *(const bf16x8*)(kr + 32);
        f32x4 s = mfma16(khi, qf1, mfma16(klo, qf0, bias[st]));
        #pragma unroll
        for (int r = 0; r < 2; r++) {
            float p0 = __builtin_amdgcn_exp2f(s[2 * r]);
            float p1 = __builtin_amdgcn_exp2f(s[2 * r + 1]);
            __hip_bfloat162 h2 = __float22bfloat162_rn(float2{p0, p1});
            short2 sp = *(short2*)&h2;
            pp[st & 1].s[(st >> 1) * 4 + 2 * r]     = sp.x;
            pp[st & 1].s[(st >> 1) * 4 + 2 * r + 1] = sp.y;
        }
    }
    #pragma unroll
    for (int nt = 0; nt < 4; nt++) {
        const short* vr = Vt + (nt * 16 + m16) * 72 + g * 8;
        bf16x8 vlo = *(const bf16x8*)vr;
        bf16x8 vhi = *(const bf16x8*)(vr + 32);
        o[nt] = mfma16(vlo, pp[0].v, o[nt]);
        o[nt] = mfma16(vhi, pp[1].v, o[nt]);
    }
    lacc = mfma16(amk0, pp[0].v, lacc);
    lacc = mfma16(amk1, pp[1].v, lacc);
}

// ---------------------------------------------------------------------------
// Kernel 4: flash attention — double-buffered LDS, ONE barrier per tile,
// K/V + bias prefetched a full tile ahead (affine pointers; tail prefetch
// overruns stay inside d_ws).
// ---------------------------------------------------------------------------
__global__ __launch_bounds__(256, 4) void attn_kernel(
    const short* __restrict__ Qrm, const short* __restrict__ Krm,
    const short* __restrict__ VT, const short* __restrict__ mkp,
    const float* __restrict__ bias_t, short* __restrict__ ctx) {
    const int b = blockIdx.z, h = blockIdx.y;
    const int q0 = blockIdx.x * 64;
    const short* VTp = VT + ((size_t)b * cH + h) * cS * cD;   // [d][kappa(s)]
    const float* bh = bias_t + h * 4096 + 2048;
    const short* mkb = mkp + b * cS;

    const int tid = threadIdx.x, wave = tid >> 6, lane = tid & 63;
    const int m16 = lane & 15, g = lane >> 4;

    __shared__ short smem[4 * 64 * 72];        // KtA VtA KtB VtB
    short* KtA = smem;
    short* VtA = smem + 4608;
    short* KtB = smem + 9216;
    short* VtB = smem + 13824;

    const int q = q0 + wave * 16 + m16;
    const short* qb = Qrm + (size_t)(b * cS + q) * cM + h * cD;
    bf16x8 qf0 = *(const bf16x8*)(qb + g * 8);
    bf16x8 qf1 = *(const bf16x8*)(qb + 32 + g * 8);

    f32x4 o[4] = {};
    f32x4 lacc = {};

    const int srow = tid >> 3, scol = (tid & 7) << 3;
    const short* kp = Krm + (size_t)b * cS * cM + h * cD + (size_t)srow * cM + scol;
    const short* vp = VTp + (size_t)srow * cS + scol;
    const float* bq = bh + g * 4 - q;          // bias base for this thread

    bf16x8 kr0, kr1, vr0, vr1;
    f32x4 bias0[4], bias1[4];

    // ---- prologue: tile 0 regs -> bufA; tile 1 regs in flight
    kr0 = *(const bf16x8*)(kp);
    kr1 = *(const bf16x8*)(kp + 32 * cM);
    vr0 = *(const bf16x8*)(vp);
    vr1 = *(const bf16x8*)(vp + 32 * cS);
    #pragma unroll
    for (int st = 0; st < 4; st++) bias0[st] = ld_f32x4_a4(bq + st * 16);
    *(bf16x8*)(KtA + srow * 72 + scol) = kr0;
    *(bf16x8*)(KtA + (srow + 32) * 72 + scol) = kr1;
    *(bf16x8*)(VtA + srow * 72 + scol) = vr0;
    *(bf16x8*)(VtA + (srow + 32) * 72 + scol) = vr1;
    kr0 = *(const bf16x8*)(kp + 64 * cM);
    kr1 = *(const bf16x8*)(kp + 96 * cM);
    vr0 = *(const bf16x8*)(vp + 64);
    vr1 = *(const bf16x8*)(vp + 32 * cS + 64);
    #pragma unroll
    for (int st = 0; st < 4; st++) bias1[st] = ld_f32x4_a4(bq + 64 + st * 16);
    __syncthreads();

    for (int kt = 0; kt < cS; kt += 128) {
        // ---- tile kt (bufA); stage kt+64 -> bufB; prefetch kt+128
        attn_tile(KtA, VtA, bias0, mkb + kt, qf0, qf1, m16, g, o, lacc);
        *(bf16x8*)(KtB + srow * 72 + scol) = kr0;
        *(bf16x8*)(KtB + (srow + 32) * 72 + scol) = kr1;
        *(bf16x8*)(VtB + srow * 72 + scol) = vr0;
        *(bf16x8*)(VtB + (srow + 32) * 72 + scol) = vr1;
        kr0 = *(const bf16x8*)(kp + (size_t)(kt + 128) * cM);
        kr1 = *(const bf16x8*)(kp + (size_t)(kt + 160) * cM);
        vr0 = *(const bf16x8*)(vp + kt + 128);
        vr1 = *(const bf16x8*)(vp + 32 * cS + kt + 128);
        #pragma unroll
        for (int st = 0; st < 4; st++)
            bias0[st] = ld_f32x4_a4(bq + kt + 128 + st * 16);
        __syncthreads();

        // ---- tile kt+64 (bufB); stage kt+128 -> bufA; prefetch kt+192
        attn_tile(KtB, VtB, bias1, mkb + kt + 64, qf0, qf1, m16, g, o, lacc);
        *(bf16x8*)(KtA + srow * 72 + scol) = kr0;
        *(bf16x8*)(KtA + (srow + 32) * 72 + scol) = kr1;
        *(bf16x8*)(VtA + srow * 72 + scol) = vr0;
        *(bf16x8*)(VtA + (srow + 32) * 72 + scol) = vr1;
        kr0 = *(const bf16x8*)(kp + (size_t)(kt + 192) * cM);
        kr1 = *(const bf16x8*)(kp + (size_t)(kt + 224) * cM);
        vr0 = *(const bf16x8*)(vp + kt + 192);
        vr1 = *(const bf16x8*)(vp + 32 * cS + kt + 192);
        #pragma unroll
        for (int st = 0; st < 4; st++)
            bias1[st] = ld_f32x4_a4(bq + kt + 192 + st * 16);
        __syncthreads();
    }

    const float inv = 1.0f / lacc[0];    // mask-weighted denominator
    short* cb = ctx + ((size_t)b * cS + q) * cM + h * cD;
    #pragma unroll
    for (int nt = 0; nt < 4; nt++) {
        union { s16x4 v; short s[4]; } pk;
        #pragma unroll
        for (int r = 0; r < 4; r++) pk.s[r] = f2bf(o[nt][r] * inv);
        *(s16x4*)(cb + nt * 16 + g * 4) = pk.v;
    }
}

// ---------------------------------------------------------------------------
// Kernel 5: out fp32 = ctx(bf16) @ WoT
// ---------------------------------------------------------------------------
__global__ __launch_bounds__(256) void gemm_o_kernel(
    const short* __restrict__ ctx, const short* __restrict__ WoT,
    float* __restrict__ out) {
    const int m0 = blockIdx.y * 128, c0 = blockIdx.x * 128;
    __shared__ short smem[8192];
    const int tid = threadIdx.x, w = tid >> 6, l = tid & 63;
    const int m16 = l & 15, g = l >> 4;
    const int mq = (w & 1) * 64, nq = (w >> 1) * 64;
    f32x4 acc[4][4] = {};
    gemm_core<false>(ctx, WoT, smem, m0, c0, tid, acc);
    #pragma unroll
    for (int i = 0; i < 4; i++)
        #pragma unroll
        for (int j = 0; j < 4; j++)
            #pragma unroll
            for (int r = 0; r < 4; r++)
                out[(size_t)(m0 + mq + i * 16 + g * 4 + r) * cM +
                    c0 + nq + j * 16 + m16] = acc[i][j][r];
}

extern "C" void kernel_launch(void* const* d_in, const int* in_sizes, int n_in,
                              void* d_out, int out_size, void* d_ws, size_t ws_size,
                              hipStream_t stream) {
    const float* hidden   = (const float*)d_in[0];
    const int*   mask     = (const int*)d_in[1];
    const float* Wq       = (const float*)d_in[2];
    const float* Wk       = (const float*)d_in[3];
    const float* Wv       = (const float*)d_in[4];
    const float* Wo       = (const float*)d_in[5];
    const float* rel_bias = (const float*)d_in[6];
    float* out = (float*)d_out;

    // ws (shorts): hbf/ctx 4M | Wt 4x1M | Q 4M | K 4M | VT 4M |
    //              bias 64K f32 | maskmul 4K f32 | mkp 4K bf16 | pad
    short* hbf_ctx = (short*)d_ws;
    short* Wt  = hbf_ctx + (size_t)4 * 1024 * 1024;
    short* Qrm = Wt  + (size_t)4 * 1024 * 1024;
    short* Krm = Qrm + (size_t)4 * 1024 * 1024;
    short* VT  = Krm + (size_t)4 * 1024 * 1024;
    float* bias_t  = (float*)(VT + (size_t)4 * 1024 * 1024);
    float* maskmul = bias_t + 16 * 4096;
    short* mkp     = (short*)(maskmul + 4096);

    bias_table_kernel<<<16, 256, 0, stream>>>(rel_bias, mask, bias_t, maskmul, mkp);
    conv_hidden_kernel<<<2048, 256, 0, stream>>>(hidden, hbf_ctx);
    conv_wt_kernel<<<dim3(16, 16, 4), 256, 0, stream>>>(Wq, Wk, Wv, Wo, Wt);
    gemm_qkv_kernel<<<dim3(8, 32, 3), 256, 0, stream>>>(hbf_ctx, Wt, maskmul,
                                                        Qrm, Krm, VT);
    attn_kernel<<<dim3(32, cH, cB), 256, 0, stream>>>(Qrm, Krm, VT, mkp, bias_t,
                                                      hbf_ctx);
    gemm_o_kernel<<<dim3(8, 32), 256, 0, stream>>>(hbf_ctx, Wt + (size_t)3 * 1024 * 1024,
                                                   out);
}